// Round 1
// baseline (2168.918 us; speedup 1.0000x reference)
//
#include <hip/hip_runtime.h>

#define EPS 1e-5f

constexpr int BATCH = 32;
constexpr int CIN   = 256;
constexpr int MID   = 64;
constexpr int COUT  = 256;
constexpr int Hh    = 112;
constexpr int Ww    = 112;
constexpr int HW    = Hh * Ww;          // 12544
constexpr int BHW   = BATCH * HW;       // 401408
constexpr int OUT0  = BATCH * COUT * HW; // 102760448  (gate tail starts here)
constexpr int T_ELEMS = BATCH * MID * HW; // 25690112

// ---------------------------------------------------------------- gate ----
__global__ void gate_kernel(const float* __restrict__ emb,
                            const float* __restrict__ gw,
                            const float* __restrict__ gb,
                            float* __restrict__ gate_ws,
                            float* __restrict__ out_gate) {
    int b = blockIdx.x;          // 0..31
    int o = threadIdx.x;         // 0..63
    const float* e = emb + b * 64;
    const float* w = gw + o * 64;
    float s = gb[o];
#pragma unroll 8
    for (int k = 0; k < 64; ++k) s += e[k] * w[k];
    s = fmaxf(s, 0.0f);
    gate_ws[b * 64 + o] = s;
    out_gate[b * 64 + o] = s;
}

// --------------------------------------------------- conv1 + bn1 + relu ---
__global__ __launch_bounds__(256) void conv1_kernel(
    const float* __restrict__ x, const float* __restrict__ w1,
    const float* __restrict__ g, const float* __restrict__ bta,
    const float* __restrict__ mean, const float* __restrict__ var,
    float* __restrict__ t1) {
    __shared__ float wT[64][64];     // [cin_chunk][out]
    __shared__ float s1[64], b1[64];
    int tid = threadIdx.x;
    int q = blockIdx.x * 256 + tid;  // global position
    int n = q / HW, p = q % HW;

    if (tid < 64) {
        float inv = rsqrtf(var[tid] + EPS) * g[tid];
        s1[tid] = inv;
        b1[tid] = bta[tid] - mean[tid] * inv;
    }

    float acc[64];
#pragma unroll
    for (int o = 0; o < 64; ++o) acc[o] = 0.0f;

    for (int c0 = 0; c0 < CIN; c0 += 64) {
        __syncthreads();
        for (int i = tid; i < 4096; i += 256) {
            int c = i >> 6, o = i & 63;
            wT[c][o] = w1[o * CIN + c0 + c];
        }
        __syncthreads();
        const float* xp = x + (n * CIN + c0) * HW + p;
#pragma unroll 4
        for (int c = 0; c < 64; ++c) {
            float v = xp[c * HW];
#pragma unroll
            for (int o = 0; o < 64; ++o) acc[o] += wT[c][o] * v;
        }
    }

    float* tp = t1 + n * MID * HW + p;
#pragma unroll
    for (int o = 0; o < 64; ++o) {
        float v = fmaxf(acc[o] * s1[o] + b1[o], 0.0f);
        tp[o * HW] = v;
    }
}

// ------------------------------------------- conv2 * gate + bn2 + relu ----
__global__ __launch_bounds__(256) void conv2_kernel(
    const float* __restrict__ t1, const float* __restrict__ w2,
    const float* __restrict__ gate,
    const float* __restrict__ g, const float* __restrict__ bta,
    const float* __restrict__ mean, const float* __restrict__ var,
    float* __restrict__ t2) {
    __shared__ float ws[16 * 9 * 64];   // [cc][k][o]  36 KB
    __shared__ float s2[64], b2[64];
    int tid = threadIdx.x;
    int q = blockIdx.x * 256 + tid;
    int n = q / HW, p = q % HW;
    int h = p / Ww, w = p % Ww;

    if (tid < 64) {
        float inv = rsqrtf(var[tid] + EPS) * g[tid];
        s2[tid] = inv;
        b2[tid] = bta[tid] - mean[tid] * inv;
    }

    float acc[64];
#pragma unroll
    for (int o = 0; o < 64; ++o) acc[o] = 0.0f;

    for (int c0 = 0; c0 < MID; c0 += 16) {
        __syncthreads();
        for (int i = tid; i < 16 * 9 * 64; i += 256) {
            int o  = i & 63;
            int k  = (i >> 6) % 9;
            int cc = i / (64 * 9);
            ws[i] = w2[(o * MID + c0 + cc) * 9 + k];
        }
        __syncthreads();
        for (int cc = 0; cc < 16; ++cc) {
            const float* tp = t1 + (n * MID + c0 + cc) * HW;
#pragma unroll
            for (int kh = 0; kh < 3; ++kh) {
                int hh = h + kh - 1;
                if ((unsigned)hh >= (unsigned)Hh) continue;
#pragma unroll
                for (int kw = 0; kw < 3; ++kw) {
                    int ww2 = w + kw - 1;
                    if ((unsigned)ww2 >= (unsigned)Ww) continue;
                    float v = tp[hh * Ww + ww2];
                    const float* wp = &ws[(cc * 9 + kh * 3 + kw) * 64];
#pragma unroll
                    for (int o = 0; o < 64; ++o) acc[o] += wp[o] * v;
                }
            }
        }
    }

    const float* gp = gate + n * 64;
    float* op = t2 + n * MID * HW + p;
#pragma unroll
    for (int o = 0; o < 64; ++o) {
        float v = acc[o] * gp[o];
        v = fmaxf(v * s2[o] + b2[o], 0.0f);
        op[o * HW] = v;
    }
}

// ------------------------------- conv3 + bn3 + residual(x) + relu ---------
__global__ __launch_bounds__(256) void conv3_kernel(
    const float* __restrict__ t2, const float* __restrict__ w3,
    const float* __restrict__ x,
    const float* __restrict__ g, const float* __restrict__ bta,
    const float* __restrict__ mean, const float* __restrict__ var,
    float* __restrict__ out) {
    __shared__ float wT[64][64];
    __shared__ float s3[64], b3[64];
    int tid = threadIdx.x;
    int q = blockIdx.x * 256 + tid;
    int n = q / HW, p = q % HW;
    int oc0 = blockIdx.y * 64;

    if (tid < 64) {
        int oc = oc0 + tid;
        float inv = rsqrtf(var[oc] + EPS) * g[oc];
        s3[tid] = inv;
        b3[tid] = bta[oc] - mean[oc] * inv;
    }
    for (int i = tid; i < 4096; i += 256) {
        int c = i >> 6, o = i & 63;
        wT[c][o] = w3[(oc0 + o) * MID + c];
    }
    __syncthreads();

    float acc[64];
#pragma unroll
    for (int o = 0; o < 64; ++o) acc[o] = 0.0f;

    const float* tp = t2 + n * MID * HW + p;
#pragma unroll 4
    for (int c = 0; c < 64; ++c) {
        float v = tp[c * HW];
#pragma unroll
        for (int o = 0; o < 64; ++o) acc[o] += wT[c][o] * v;
    }

    const float* xp = x + (n * CIN + oc0) * HW + p;
    float* op = out + (n * CIN + oc0) * HW + p;
#pragma unroll
    for (int o = 0; o < 64; ++o) {
        float v = acc[o] * s3[o] + b3[o] + xp[o * HW];
        op[o * HW] = fmaxf(v, 0.0f);
    }
}

// --------------------------------------------------------------------------
extern "C" void kernel_launch(void* const* d_in, const int* in_sizes, int n_in,
                              void* d_out, int out_size, void* d_ws, size_t ws_size,
                              hipStream_t stream) {
    const float* x     = (const float*)d_in[0];
    const float* emb   = (const float*)d_in[1];
    const float* w1    = (const float*)d_in[2];
    const float* bn1_g = (const float*)d_in[3];
    const float* bn1_b = (const float*)d_in[4];
    const float* bn1_m = (const float*)d_in[5];
    const float* bn1_v = (const float*)d_in[6];
    const float* w2    = (const float*)d_in[7];
    const float* bn2_g = (const float*)d_in[8];
    const float* bn2_b = (const float*)d_in[9];
    const float* bn2_m = (const float*)d_in[10];
    const float* bn2_v = (const float*)d_in[11];
    const float* w3    = (const float*)d_in[12];
    const float* bn3_g = (const float*)d_in[13];
    const float* bn3_b = (const float*)d_in[14];
    const float* bn3_m = (const float*)d_in[15];
    const float* bn3_v = (const float*)d_in[16];
    const float* gw    = (const float*)d_in[17];
    const float* gb    = (const float*)d_in[18];

    float* out = (float*)d_out;

    float* t1   = (float*)d_ws;
    float* t2   = t1 + T_ELEMS;
    float* gate = t2 + T_ELEMS;

    gate_kernel<<<BATCH, 64, 0, stream>>>(emb, gw, gb, gate, out + OUT0);

    conv1_kernel<<<BHW / 256, 256, 0, stream>>>(
        x, w1, bn1_g, bn1_b, bn1_m, bn1_v, t1);

    conv2_kernel<<<BHW / 256, 256, 0, stream>>>(
        t1, w2, gate, bn2_g, bn2_b, bn2_m, bn2_v, t2);

    conv3_kernel<<<dim3(BHW / 256, 4), 256, 0, stream>>>(
        t2, w3, x, bn3_g, bn3_b, bn3_m, bn3_v, out);
}